// Round 4
// baseline (499.101 us; speedup 1.0000x reference)
//
#include <hip/hip_runtime.h>
#include <hip/hip_fp16.h>
#include <math.h>

namespace {
constexpr int S = 192;
constexpr long long S2 = (long long)S * S;
constexpr long long S3 = (long long)S * S2;
constexpr int NB = 4;
constexpr int K = 11;
constexpr int R = 5;
constexpr int HCH = 32;   // A: h-outputs per block (6 chunks)
constexpr int DCH = 16;   // B: d-outputs per block (12 chunks)  [R10: was 48]
constexpr int AROW = 208; // A LDS row: [8 pad][192 data][8 pad], 16B-aligned data
constexpr float C1f = 1e-4f;
constexpr float C2f = 9e-4f;

struct GaussW { float g[K]; };

__global__ void k_init(double* acc) { *acc = 0.0; }

__global__ void k_final(const double* __restrict__ acc, float* __restrict__ out) {
  out[0] = (float)(acc[0] / (double)(NB * S3));
}

// ======================= Kernel A =======================
// Fused W+H blur. Fields 0..3 (mux,muy,bxx,byy) packed as 4xfp16 in uint2;
// field 4 (bxy) separate fp16.
// R10: double-buffered LDS staged via global_load_lds DMA (width 16, zero
// VGPR cost — R7/R9 showed any register staging crosses the 84-VGPR
// occupancy cliff). Batch k+1's DMA issues BEFORE consume of batch k, so
// the ~3200-cycle consume covers the load latency and the compiler's
// vmcnt(0) drain at the next barrier is ~free. 4 barriers (was 8).
// Arithmetic identical to R6/R8 (same taps, same fmaf order).

__device__ __forceinline__ void gll16(const float* gsrc, float* ldst) {
  // LDS dest = wave-uniform base + lane*16 (HW); global src is per-lane.
  __builtin_amdgcn_global_load_lds(
      (const __attribute__((address_space(1))) void*)gsrc,
      (__attribute__((address_space(3))) void*)ldst, 16, 0, 0);
}

// Issue one batch's staging: units = (arr, row), 2*NROWS units round-robin
// across 3 waves. Per unit: 48 lanes x 16B = one 192-float row -> LDS[8..199].
// Guarded (out-of-range) rows: ds_write zeros instead (uniform branch).
template <int NROWS, bool GUARD>
__device__ __forceinline__ void issueA(const float* pg, const float* pp,
                                       int r0, int l, int v,
                                       float (*buf)[K][AROW]) {
#pragma unroll
  for (int k = 0; k < (2 * NROWS + 2) / 3; ++k) {
    int u = v + 3 * k;
    if (u < 2 * NROWS) {
      int row = u >> 1, arr = u & 1;
      int r = r0 + row;
      float* dst = &buf[arr][row][8];
      if (!GUARD || (unsigned)r < (unsigned)S) {
        const float* src = (arr ? pp : pg) + (long long)r * S + (l << 2);
        if (l < 48) gll16(src, dst);
      } else {
        if (l < 48) *(float4*)(dst + (l << 2)) = make_float4(0.f, 0.f, 0.f, 0.f);
      }
    }
  }
}

template <int NROWS, bool EMITALL>
__device__ __forceinline__ void consumeA(
    const float (*LA)[AROW], const float (*LB)[AROW], int w, const GaussW& Wt,
    float2 (&w01)[K], float2 (&w23)[K], float (&w4v)[K],
    uint2* p0123, __half* p4, long long obase, int hbase) {
#pragma unroll
  for (int j = 0; j < NROWS; ++j) {
    // W-blur the 5 products for staged row j
    float2 s01 = make_float2(0.f, 0.f), s23 = make_float2(0.f, 0.f);
    float s4 = 0.f;
#pragma unroll
    for (int i = 0; i < K; ++i) {
      float a = LA[j][w + 3 + i];
      float b = LB[j][w + 3 + i];
      float g = Wt.g[i];
      s01.x = fmaf(g, a, s01.x);
      s01.y = fmaf(g, b, s01.y);
      float ta = g * a, tb = g * b;
      s23.x = fmaf(ta, a, s23.x);
      s23.y = fmaf(tb, b, s23.y);
      s4 = fmaf(ta, b, s4);
    }
    w01[j] = s01; w23[j] = s23; w4v[j] = s4;  // ring slot = counter % 11 = j
    if (EMITALL || j == K - 1) {              // compile-time
      float2 m01 = make_float2(0.f, 0.f), m23 = make_float2(0.f, 0.f);
      float m4 = 0.f;
#pragma unroll
      for (int i = 0; i < K; ++i) {
        const int sl = (j + 1 + i) % K;       // compile-time
        float g = Wt.g[i];
        m01.x = fmaf(g, w01[sl].x, m01.x);
        m01.y = fmaf(g, w01[sl].y, m01.y);
        m23.x = fmaf(g, w23[sl].x, m23.x);
        m23.y = fmaf(g, w23[sl].y, m23.y);
        m4 = fmaf(g, w4v[sl], m4);
      }
      long long o = obase + (long long)(hbase + j) * S;
      __half2 h01 = __floats2half2_rn(m01.x, m01.y);
      __half2 h23 = __floats2half2_rn(m23.x, m23.y);
      uint2 v;
      v.x = __builtin_bit_cast(unsigned, h01);
      v.y = __builtin_bit_cast(unsigned, h23);
      p0123[o] = v;
      p4[o] = __float2half(m4);
    }
  }
}

// grid = (dz=S, hchunk=6, n); block = 192 (w). Batches of 11,11,11,9 rows;
// 2 x 18.3 KB LDS buffers (4 blocks/CU), 1 barrier per batch.
// Row ranges: b0 = h0-5..h0+5 (GUARD: neg), b1 <= 176, b2 <= 187 (safe),
// b3 = h0+28..h0+36 <= 196 (GUARD).
__global__ __launch_bounds__(192) void k_blurWH(
    const float* __restrict__ gt, const float* __restrict__ pr,
    uint2* __restrict__ p0123, __half* __restrict__ p4,
    long long in_base, GaussW Wt) {
  __shared__ float lds[2][2][K][AROW];  // [buf][arr(gt/pr)][row][col]
  const int w = threadIdx.x;
  const int l = w & 63;
  const int v = w >> 6;
  const int dz = blockIdx.x;
  const int h0 = (int)blockIdx.y * HCH;
  const long long n = blockIdx.z;
  const float* pg = gt + in_base + (n * S + dz) * S2;
  const float* pp = pr + in_base + (n * S + dz) * S2;
  const long long obase = (n * S + dz) * S2 + w;

  // zero halo pads once: 44 rows x 16 pad floats ([0..7],[200..207]) = 704.
  // Pads are disjoint from the DMA region [8..199] -> no race with gll16.
  for (int q = w; q < 704; q += 192) {
    int prw = q >> 4, p = q & 15;
    int idx = (p < 8) ? p : (192 + p);
    (&lds[0][0][0][0])[prw * AROW + idx] = 0.f;
  }

  float2 w01[K], w23[K];
  float w4v[K];  // no init needed: batch0 writes all 11 slots before 1st emit

  issueA<K, true>(pg, pp, h0 - R, l, v, lds[0]);
  __syncthreads();                                  // buf0 ready (pads too)
  issueA<K, false>(pg, pp, h0 + 6, l, v, lds[1]);   // DMA b1 under consume b0
  consumeA<K, false>(lds[0][0], lds[0][1], w, Wt, w01, w23, w4v,
                     p0123, p4, obase, h0 - 10);
  __syncthreads();                                  // buf1 ready, buf0 free
  issueA<K, false>(pg, pp, h0 + 17, l, v, lds[0]);
  consumeA<K, true>(lds[1][0], lds[1][1], w, Wt, w01, w23, w4v,
                    p0123, p4, obase, h0 + 1);
  __syncthreads();
  issueA<9, true>(pg, pp, h0 + 28, l, v, lds[1]);
  consumeA<K, true>(lds[0][0], lds[0][1], w, Wt, w01, w23, w4v,
                    p0123, p4, obase, h0 + 12);
  __syncthreads();
  consumeA<9, true>(lds[1][0], lds[1][1], w, Wt, w01, w23, w4v,
                    p0123, p4, obase, h0 + 23);
}

// ======================= Kernel B =======================
// R10: DCH 48 -> 16 (12 chunks): 3x block-level parallelism, per-thread
// serial chain 48 -> 16 outputs, and ALL stage loads (11+5 planes) issue
// before any consume. Re-read factor 1.21 -> 1.63x, but reads are
// L3-resident under nb=2 chunking. Per-output arithmetic unchanged.

template <int N, bool GUARD>
__device__ __forceinline__ void stageB(const uint2* q0123, const __half* q4,
                                       int plane0, uint2 (&sab)[N], __half (&se)[N]) {
#pragma unroll
  for (int j = 0; j < N; ++j) {
    int d = plane0 + j;
    bool ok = !GUARD || ((unsigned)d < (unsigned)S);
    long long o = (long long)d * S2;
    sab[j] = ok ? q0123[o] : make_uint2(0u, 0u);  // fp16 bits 0 == 0.0
    se[j] = ok ? q4[o] : __float2half(0.f);
  }
}

template <int NOUT>
__device__ __forceinline__ void consumeB(
    const uint2 (&sab)[NOUT], const __half (&se)[NOUT],
    const GaussW& Wt, float2 (&r01)[K], float2 (&r23)[K], float (&r4)[K],
    double& lsum) {
  float fsum = 0.f;
#pragma unroll
  for (int j = 0; j < NOUT; ++j) {
    const int sw = (10 + j) % K;              // compile-time commit slot
    r01[sw] = __half22float2(__builtin_bit_cast(__half2, sab[j].x));
    r23[sw] = __half22float2(__builtin_bit_cast(__half2, sab[j].y));
    r4[sw] = __half2float(se[j]);
    float2 m01 = make_float2(0.f, 0.f), m23 = make_float2(0.f, 0.f);
    float m4 = 0.f;
#pragma unroll
    for (int i = 0; i < K; ++i) {
      const int sl = (j + i) % K;             // compile-time
      float g = Wt.g[i];
      m01.x = fmaf(g, r01[sl].x, m01.x);
      m01.y = fmaf(g, r01[sl].y, m01.y);
      m23.x = fmaf(g, r23[sl].x, m23.x);
      m23.y = fmaf(g, r23[sl].y, m23.y);
      m4 = fmaf(g, r4[sl], m4);
    }
    float mux = m01.x, muy = m01.y, bxx = m23.x, byy = m23.y, bxy = m4;
    float mux2 = mux * mux, muy2 = muy * muy, muxy = mux * muy;
    float sx = bxx - mux2, sy = byy - muy2, sxy = bxy - muxy;
    float num = fmaf(2.f, muxy, C1f) * fmaf(2.f, sxy, C2f);
    float den = (mux2 + muy2 + C1f) * (sx + sy + C2f);
    fsum += 1.f - num * __builtin_amdgcn_rcpf(den);
  }
  lsum += (double)fsum;
}

// D-blur + SSIM + mean-reduce. grid = (h=S, n, dchunk=12); block = 192 (w).
// Register ring of 11 planes; all 16 stage planes issued up front.
__global__ __launch_bounds__(192) void k_blurD_ssim(
    const uint2* __restrict__ p0123, const __half* __restrict__ p4,
    double* __restrict__ acc, GaussW Wt) {
  const int w = threadIdx.x;
  const int h = blockIdx.x;
  const long long n = blockIdx.y;
  const int d0 = (int)blockIdx.z * DCH;
  const long long base = n * S3 + (long long)h * S + w;
  const uint2* q0123 = p0123 + base;
  const __half* q4 = p4 + base;

  float2 r01[K], r23[K];
  float r4[K];
  // preload counters 0..9 -> slots 0..9 (planes d0-5..d0+4; d0+4 <= 180)
#pragma unroll
  for (int c = 0; c < K - 1; ++c) {
    int d = d0 - R + c;
    if ((unsigned)d < (unsigned)S) {
      long long o = (long long)d * S2;
      uint2 vv = q0123[o];
      r01[c] = __half22float2(__builtin_bit_cast(__half2, vv.x));
      r23[c] = __half22float2(__builtin_bit_cast(__half2, vv.y));
      r4[c] = __half2float(q4[o]);
    } else {
      r01[c] = make_float2(0.f, 0.f);
      r23[c] = make_float2(0.f, 0.f);
      r4[c] = 0.f;
    }
  }
  r01[K - 1] = make_float2(0.f, 0.f);
  r23[K - 1] = make_float2(0.f, 0.f);
  r4[K - 1] = 0.f;

  uint2 sab0[K], sab1[5];
  __half se0[K], se1[5];
  double lsum = 0.0;

  // counters: preload 0..9; sab0 = 10..20 (planes d0+5..d0+15 <= 191, no
  // guard); sab1 = 21..25 (planes d0+16..d0+20 <= 196, guard hi).
  stageB<K, false>(q0123, q4, d0 + 5, sab0, se0);
  stageB<5, true>(q0123, q4, d0 + 16, sab1, se1);
  consumeB<K>(sab0, se0, Wt, r01, r23, r4, lsum);   // t = 0..10
  consumeB<5>(sab1, se1, Wt, r01, r23, r4, lsum);   // t = 11..15

  // block reduction: wave shuffle -> LDS -> one atomic per block
  double vv = lsum;
#pragma unroll
  for (int o = 32; o > 0; o >>= 1) vv += __shfl_down(vv, o, 64);
  __shared__ double wsum[3];
  int lane = threadIdx.x & 63, wv = threadIdx.x >> 6;
  if (lane == 0) wsum[wv] = vv;
  __syncthreads();
  if (threadIdx.x == 0) atomicAdd(acc, wsum[0] + wsum[1] + wsum[2]);
}

}  // namespace

extern "C" void kernel_launch(void* const* d_in, const int* in_sizes, int n_in,
                              void* d_out, int out_size, void* d_ws, size_t ws_size,
                              hipStream_t stream) {
  (void)in_sizes; (void)n_in; (void)out_size;
  const float* gt = (const float*)d_in[0];
  const float* pr = (const float*)d_in[1];
  float* out = (float*)d_out;
  double* acc = (double*)d_ws;

  GaussW W;
  {
    double gg[K], sum = 0.0;
    for (int i = 0; i < K; ++i) {
      double x = (double)(i - K / 2);
      gg[i] = exp(-(x * x) / (2.0 * 1.5 * 1.5)) / (sqrt(2.0 * M_PI) * 1.5);
      sum += gg[i];
    }
    for (int i = 0; i < K; ++i) W.g[i] = (float)(gg[i] / sum);
  }

  auto run = [&](long long base_n, int nb) {
    size_t vox = (size_t)nb * S3;
    uint2* p0123 = (uint2*)((char*)d_ws + 256);
    __half* p4 = (__half*)(p0123 + vox);
    k_blurWH<<<dim3(S, S / HCH, nb), dim3(192), 0, stream>>>(
        gt, pr, p0123, p4, base_n * S3, W);
    k_blurD_ssim<<<dim3(S, nb, S / DCH), dim3(192), 0, stream>>>(
        p0123, p4, acc, W);
  };
  auto need = [](int nb) { return (size_t)256 + (size_t)nb * S3 * 10; };  // 8+2 B/voxel

  k_init<<<dim3(1), dim3(1), 0, stream>>>(acc);
  // R8: nb=2 chunks keep the 141 MB per-chunk intermediate (plus 113 MB
  // inputs) mostly L3-resident.
  if (ws_size >= need(2)) {
    run(0, 2);
    run(2, 2);
  } else {
    for (int g = 0; g < NB; ++g) run(g, 1);
  }
  k_final<<<dim3(1), dim3(1), 0, stream>>>(acc, out);
}

// Round 5
// 493.238 us; speedup vs baseline: 1.0119x; 1.0119x over previous
//
#include <hip/hip_runtime.h>
#include <hip/hip_fp16.h>
#include <math.h>

namespace {
constexpr int S = 192;
constexpr long long S2 = (long long)S * S;
constexpr long long S3 = (long long)S * S2;
constexpr int NB = 4;
constexpr int K = 11;
constexpr int R = 5;
constexpr int HCH = 32;   // A: h-outputs per block (6 chunks)
constexpr int DCH = 48;   // B: d-outputs per block (4 chunks) [R8-proven]
constexpr float C1f = 1e-4f;
constexpr float C2f = 9e-4f;

struct GaussW { float g[K]; };

__global__ void k_init(double* acc) { *acc = 0.0; }

__global__ void k_final(const double* __restrict__ acc, float* __restrict__ out) {
  out[0] = (float)(acc[0] / (double)(NB * S3));
}

// ======================= Body A (R8-proven, verbatim math) =======================
// Fused W+H blur. Fields 0..3 (mux,muy,bxx,byy) packed as 4xfp16 in uint2;
// field 4 (bxy) separate fp16. Loads go straight to LDS within stageA;
// TLP hides the latency. R11: body factored out so it can run either as a
// standalone dispatch or inside the mixed dispatch. Buffers are now
// CHUNK-LOCAL (one n per dispatch), so obase has no n term.

template <int NROWS, bool GUARD>
__device__ __forceinline__ void stageA(const float* pg, const float* pp, int r0,
                                       int w, float2 (*rb)[208]) {
  float la[NROWS], lb[NROWS];  // transient: dead before consume
#pragma unroll
  for (int j = 0; j < NROWS; ++j) {
    int r = r0 + j;
    bool ok = !GUARD || ((unsigned)r < (unsigned)S);
    la[j] = ok ? pg[(long long)r * S + w] : 0.f;
    lb[j] = ok ? pp[(long long)r * S + w] : 0.f;
  }
#pragma unroll
  for (int j = 0; j < NROWS; ++j) rb[j][8 + w] = make_float2(la[j], lb[j]);
}

template <int NROWS, bool EMITALL>
__device__ __forceinline__ void consumeA(
    const float2 (*rb)[208], int w, const GaussW& Wt,
    float2 (&w01)[K], float2 (&w23)[K], float (&w4v)[K],
    uint2* p0123, __half* p4, long long obase, int hbase) {
#pragma unroll
  for (int j = 0; j < NROWS; ++j) {
    // W-blur the 5 products for staged row j
    float2 s01 = make_float2(0.f, 0.f), s23 = make_float2(0.f, 0.f);
    float s4 = 0.f;
#pragma unroll
    for (int i = 0; i < K; ++i) {
      float2 ab = rb[j][w + 3 + i];
      float g = Wt.g[i];
      s01.x = fmaf(g, ab.x, s01.x);
      s01.y = fmaf(g, ab.y, s01.y);
      float ta = g * ab.x, tb = g * ab.y;
      s23.x = fmaf(ta, ab.x, s23.x);
      s23.y = fmaf(tb, ab.y, s23.y);
      s4 = fmaf(ta, ab.y, s4);
    }
    w01[j] = s01; w23[j] = s23; w4v[j] = s4;  // ring slot = counter % 11 = j
    if (EMITALL || j == K - 1) {              // compile-time
      float2 m01 = make_float2(0.f, 0.f), m23 = make_float2(0.f, 0.f);
      float m4 = 0.f;
#pragma unroll
      for (int i = 0; i < K; ++i) {
        const int sl = (j + 1 + i) % K;       // compile-time
        float g = Wt.g[i];
        m01.x = fmaf(g, w01[sl].x, m01.x);
        m01.y = fmaf(g, w01[sl].y, m01.y);
        m23.x = fmaf(g, w23[sl].x, m23.x);
        m23.y = fmaf(g, w23[sl].y, m23.y);
        m4 = fmaf(g, w4v[sl], m4);
      }
      long long o = obase + (long long)(hbase + j) * S;
      __half2 h01 = __floats2half2_rn(m01.x, m01.y);
      __half2 h23 = __floats2half2_rn(m23.x, m23.y);
      uint2 v;
      v.x = __builtin_bit_cast(unsigned, h01);
      v.y = __builtin_bit_cast(unsigned, h23);
      p0123[o] = v;
      p4[o] = __float2half(m4);
    }
  }
}

// Batches of 11,11,11,9 rows; single 18.4 KB LDS buffer, 2 barriers/batch.
// Row ranges: b0 = h0-5..h0+5 (GUARD: neg), b1 <= 176, b2 <= 187 (safe),
// b3 = h0+28..h0+36 <= 196 (GUARD).
__device__ __forceinline__ void bodyA(
    const float* __restrict__ gt, const float* __restrict__ pr,
    uint2* __restrict__ p0123, __half* __restrict__ p4,
    long long in_base, const GaussW& Wt, int dz, int h0, int w,
    float2 (*rowbuf)[208]) {
  const float* pg = gt + in_base + (long long)dz * S2;
  const float* pp = pr + in_base + (long long)dz * S2;
  const long long obase = (long long)dz * S2 + w;

  if (w < 176) {  // zero halo pads once (before first barrier)
    int j = w >> 4, q = w & 15;
    rowbuf[j][(q < 8) ? q : (192 + q)] = make_float2(0.f, 0.f);
  }

  float2 w01[K], w23[K];
  float w4v[K];  // no init needed: batch0 writes all 11 slots before 1st emit

  stageA<K, true>(pg, pp, h0 - R, w, rowbuf);
  __syncthreads();
  consumeA<K, false>(rowbuf, w, Wt, w01, w23, w4v, p0123, p4, obase, h0 - 10);
  __syncthreads();
  stageA<K, false>(pg, pp, h0 + 6, w, rowbuf);
  __syncthreads();
  consumeA<K, true>(rowbuf, w, Wt, w01, w23, w4v, p0123, p4, obase, h0 + 1);
  __syncthreads();
  stageA<K, false>(pg, pp, h0 + 17, w, rowbuf);
  __syncthreads();
  consumeA<K, true>(rowbuf, w, Wt, w01, w23, w4v, p0123, p4, obase, h0 + 12);
  __syncthreads();
  stageA<9, true>(pg, pp, h0 + 28, w, rowbuf);
  __syncthreads();
  consumeA<9, true>(rowbuf, w, Wt, w01, w23, w4v, p0123, p4, obase, h0 + 23);
}

// ======================= Body B (R8-proven, verbatim math) =======================

template <int N, bool GUARD>
__device__ __forceinline__ void stageB(const uint2* q0123, const __half* q4,
                                       int plane0, uint2 (&sab)[K], __half (&se)[K]) {
#pragma unroll
  for (int j = 0; j < N; ++j) {
    int d = plane0 + j;
    bool ok = !GUARD || ((unsigned)d < (unsigned)S);
    long long o = (long long)d * S2;
    sab[j] = ok ? q0123[o] : make_uint2(0u, 0u);  // fp16 bits 0 == 0.0
    se[j] = ok ? q4[o] : __float2half(0.f);
  }
}

template <int NOUT>
__device__ __forceinline__ void consumeB(
    const uint2 (&sab)[K], const __half (&se)[K],
    const GaussW& Wt, float2 (&r01)[K], float2 (&r23)[K], float (&r4)[K],
    double& lsum) {
  float fsum = 0.f;
#pragma unroll
  for (int j = 0; j < NOUT; ++j) {
    const int sw = (10 + j) % K;              // compile-time commit slot
    r01[sw] = __half22float2(__builtin_bit_cast(__half2, sab[j].x));
    r23[sw] = __half22float2(__builtin_bit_cast(__half2, sab[j].y));
    r4[sw] = __half2float(se[j]);
    float2 m01 = make_float2(0.f, 0.f), m23 = make_float2(0.f, 0.f);
    float m4 = 0.f;
#pragma unroll
    for (int i = 0; i < K; ++i) {
      const int sl = (j + i) % K;             // compile-time
      float g = Wt.g[i];
      m01.x = fmaf(g, r01[sl].x, m01.x);
      m01.y = fmaf(g, r01[sl].y, m01.y);
      m23.x = fmaf(g, r23[sl].x, m23.x);
      m23.y = fmaf(g, r23[sl].y, m23.y);
      m4 = fmaf(g, r4[sl], m4);
    }
    float mux = m01.x, muy = m01.y, bxx = m23.x, byy = m23.y, bxy = m4;
    float mux2 = mux * mux, muy2 = muy * muy, muxy = mux * muy;
    float sx = bxx - mux2, sy = byy - muy2, sxy = bxy - muxy;
    float num = fmaf(2.f, muxy, C1f) * fmaf(2.f, sxy, C2f);
    float den = (mux2 + muy2 + C1f) * (sx + sy + C2f);
    fsum += 1.f - num * __builtin_amdgcn_rcpf(den);
  }
  lsum += (double)fsum;
}

// D-blur + SSIM + mean-reduce. Register ring of 11 planes, ping-pong
// staging one 11-batch ahead. Chunk-local buffer (no n term).
__device__ __forceinline__ void bodyB(
    const uint2* __restrict__ p0123, const __half* __restrict__ p4,
    double* __restrict__ acc, const GaussW& Wt, int h, int d0, int w,
    double* wsum /* >=3 doubles of LDS */) {
  const long long base = (long long)h * S + w;
  const uint2* q0123 = p0123 + base;
  const __half* q4 = p4 + base;

  float2 r01[K], r23[K];
  float r4[K];
  // preload counters 0..9 -> slots 0..9 (planes d0-5..d0+4, guard low)
#pragma unroll
  for (int c = 0; c < K - 1; ++c) {
    int d = d0 - R + c;
    if ((unsigned)d < (unsigned)S) {
      long long o = (long long)d * S2;
      uint2 v = q0123[o];
      r01[c] = __half22float2(__builtin_bit_cast(__half2, v.x));
      r23[c] = __half22float2(__builtin_bit_cast(__half2, v.y));
      r4[c] = __half2float(q4[o]);
    } else {
      r01[c] = make_float2(0.f, 0.f);
      r23[c] = make_float2(0.f, 0.f);
      r4[c] = 0.f;
    }
  }
  r01[K - 1] = make_float2(0.f, 0.f);
  r23[K - 1] = make_float2(0.f, 0.f);
  r4[K - 1] = 0.f;

  uint2 sab0[K], sab1[K];
  __half se0[K], se1[K];
  double lsum = 0.0;

  // plane ranges: d0+5..15, d0+16..26, d0+27..37 (max 181: safe);
  // d0+38..48 and d0+49..52 guarded (max 196).
  stageB<K, false>(q0123, q4, d0 + 5, sab0, se0);   // counters 10..20
  stageB<K, false>(q0123, q4, d0 + 16, sab1, se1);  // counters 21..31
  consumeB<K>(sab0, se0, Wt, r01, r23, r4, lsum);   // t = 0..10
  stageB<K, false>(q0123, q4, d0 + 27, sab0, se0);  // counters 32..42
  consumeB<K>(sab1, se1, Wt, r01, r23, r4, lsum);   // t = 11..21
  stageB<K, true>(q0123, q4, d0 + 38, sab1, se1);   // counters 43..53
  consumeB<K>(sab0, se0, Wt, r01, r23, r4, lsum);   // t = 22..32
  stageB<4, true>(q0123, q4, d0 + 49, sab0, se0);   // counters 54..57
  consumeB<K>(sab1, se1, Wt, r01, r23, r4, lsum);   // t = 33..43
  consumeB<4>(sab0, se0, Wt, r01, r23, r4, lsum);   // t = 44..47

  // block reduction: wave shuffle -> LDS -> one atomic per block
  double v = lsum;
#pragma unroll
  for (int o = 32; o > 0; o >>= 1) v += __shfl_down(v, o, 64);
  int lane = w & 63, wv = w >> 6;
  if (lane == 0) wsum[wv] = v;
  __syncthreads();
  if (w == 0) atomicAdd(acc, wsum[0] + wsum[1] + wsum[2]);
}

// ======================= Dispatch wrappers =======================

// Standalone A: grid (dz=S, hchunk=6); one chunk (n folded into in_base).
__global__ __launch_bounds__(192) void k_blurWH(
    const float* __restrict__ gt, const float* __restrict__ pr,
    uint2* __restrict__ p0123, __half* __restrict__ p4,
    long long in_base, GaussW Wt) {
  __shared__ float2 rowbuf[K][208];
  bodyA(gt, pr, p0123, p4, in_base, Wt, (int)blockIdx.x,
        (int)blockIdx.y * HCH, (int)threadIdx.x, rowbuf);
}

// Standalone B: grid (h=S, dchunk=4); one chunk.
__global__ __launch_bounds__(192) void k_blurD_ssim(
    const uint2* __restrict__ p0123, const __half* __restrict__ p4,
    double* __restrict__ acc, GaussW Wt) {
  __shared__ double wsum[3];
  bodyB(p0123, p4, acc, Wt, (int)blockIdx.x, (int)blockIdx.y * DCH,
        (int)threadIdx.x, wsum);
}

// R11: mixed dispatch. B-blocks (chunk i, buffer bi) and A-blocks (chunk
// i+1, buffer 1-bi) are data-independent and co-resident: A's VALU-heavy
// phases hide B's plane-walk latency and vice versa. B-blocks come first
// in the grid so their long-latency loads start early. Flat 1-D grid of
// nB + nA blocks; branch is block-uniform.
__global__ __launch_bounds__(192) void k_mixed(
    const float* __restrict__ gt, const float* __restrict__ pr,
    uint2* __restrict__ pA0123, __half* __restrict__ pA4, long long inA_base,
    const uint2* __restrict__ pB0123, const __half* __restrict__ pB4,
    double* __restrict__ acc, GaussW Wt, int nB) {
  __shared__ float2 rowbuf[K][208];  // A uses all; B aliases first 24 B
  const int bid = (int)blockIdx.x;
  const int w = (int)threadIdx.x;
  if (bid < nB) {
    int h = bid % S, dc = bid / S;
    bodyB(pB0123, pB4, acc, Wt, h, dc * DCH, w, (double*)rowbuf);
  } else {
    int b = bid - nB;
    int dz = b % S, hc = b / S;
    bodyA(gt, pr, pA0123, pA4, inA_base, Wt, dz, hc * HCH, w, rowbuf);
  }
}

}  // namespace

extern "C" void kernel_launch(void* const* d_in, const int* in_sizes, int n_in,
                              void* d_out, int out_size, void* d_ws, size_t ws_size,
                              hipStream_t stream) {
  (void)in_sizes; (void)n_in; (void)out_size;
  const float* gt = (const float*)d_in[0];
  const float* pr = (const float*)d_in[1];
  float* out = (float*)d_out;
  double* acc = (double*)d_ws;

  GaussW W;
  {
    double gg[K], sum = 0.0;
    for (int i = 0; i < K; ++i) {
      double x = (double)(i - K / 2);
      gg[i] = exp(-(x * x) / (2.0 * 1.5 * 1.5)) / (sqrt(2.0 * M_PI) * 1.5);
      sum += gg[i];
    }
    for (int i = 0; i < K; ++i) W.g[i] = (float)(gg[i] / sum);
  }

  // Two chunk-local (nb=1) intermediate buffers, ping-pong. Each buffer:
  // p0123 = 8 B/vox (56.6 MB) + p4 = 2 B/vox (14.2 MB) = 70.8 MB; both
  // fit L3 together with the next chunk's 56.6 MB of inputs.
  const size_t bufBytes = (size_t)S3 * 10;
  const size_t need2 = 256 + 2 * bufBytes;
  const size_t need1 = 256 + bufBytes;
  char* wsb = (char*)d_ws + 256;
  uint2* p0[2];
  __half* p4b[2];
  p0[0] = (uint2*)wsb;
  p4b[0] = (__half*)(p0[0] + (size_t)S3);
  p0[1] = (uint2*)(wsb + bufBytes);
  p4b[1] = (__half*)(p0[1] + (size_t)S3);

  const int nB = S * (S / DCH);        // 768
  const int nA = S * (S / HCH);        // 1152

  k_init<<<dim3(1), dim3(1), 0, stream>>>(acc);
  if (ws_size >= need2) {
    // A0 | M(B0+A1) | M(B1+A2) | M(B2+A3) | B3
    k_blurWH<<<dim3(S, S / HCH), dim3(192), 0, stream>>>(
        gt, pr, p0[0], p4b[0], 0, W);
    for (int c = 1; c < NB; ++c) {
      k_mixed<<<dim3(nB + nA), dim3(192), 0, stream>>>(
          gt, pr, p0[c & 1], p4b[c & 1], (long long)c * S3,
          p0[(c - 1) & 1], p4b[(c - 1) & 1], acc, W, nB);
    }
    k_blurD_ssim<<<dim3(S, S / DCH), dim3(192), 0, stream>>>(
        p0[(NB - 1) & 1], p4b[(NB - 1) & 1], acc, W);
  } else {
    (void)need1;  // serial fallback: one buffer, A then B per chunk
    for (int c = 0; c < NB; ++c) {
      k_blurWH<<<dim3(S, S / HCH), dim3(192), 0, stream>>>(
          gt, pr, p0[0], p4b[0], (long long)c * S3, W);
      k_blurD_ssim<<<dim3(S, S / DCH), dim3(192), 0, stream>>>(
          p0[0], p4b[0], acc, W);
    }
  }
  k_final<<<dim3(1), dim3(1), 0, stream>>>(acc, out);
}